// Round 13
// baseline (337.664 us; speedup 1.0000x reference)
//
#include <hip/hip_runtime.h>
#include <hip/hip_bf16.h>
#include <math.h>

#define BB 48
#define TT 256
#define DD 1024
#define NB 32

typedef __attribute__((ext_vector_type(8))) short bf16x8;
typedef __attribute__((ext_vector_type(4))) float f32x4;
typedef unsigned short u16;

__device__ __forceinline__ u16 bfb(float x) {
  __hip_bfloat16 h = __float2bfloat16(x);   // RNE
  return __builtin_bit_cast(u16, h);
}
__device__ __forceinline__ float fromb(u16 u) {
  unsigned v = (unsigned)u << 16;
  return __builtin_bit_cast(float, v);
}
__device__ __forceinline__ float rdlane(float v, int l) {
  return __builtin_bit_cast(float, __builtin_amdgcn_readlane(__builtin_bit_cast(int, v), l));
}
__device__ __forceinline__ void gl16(const void* g, void* l) {
  __builtin_amdgcn_global_load_lds((const __attribute__((address_space(1))) unsigned int*)g,
                                   (__attribute__((address_space(3))) unsigned int*)l, 16, 0, 0);
}

// Fused prep: [0,NSPLIT) split(inp); [NSPLIT,NSPLIT+2048) transpose+split W;
// last block: c0 = s*bq.bk. Each block takes exactly one role (block-uniform).
#define NSPLIT 12288
__global__ __launch_bounds__(256) void prep_kernel(
    const float* __restrict__ inp, const float* __restrict__ Wq, const float* __restrict__ Wk,
    const float* __restrict__ bq, const float* __restrict__ bk,
    u16* __restrict__ inpHi, u16* __restrict__ inpLo,
    u16* __restrict__ WqTh, u16* __restrict__ WqTl,
    u16* __restrict__ WkTh, u16* __restrict__ WkTl,
    float* __restrict__ c0f) {
  __shared__ float t[32][33];
  __shared__ float ws4[4];
  const int bid = blockIdx.x, tid = threadIdx.x;
  if (bid < NSPLIT) {
    const int idx = bid * 256 + tid;
    float4 v = ((const float4*)inp)[idx];
    ushort4 h, l;
    h.x = bfb(v.x); l.x = bfb(v.x - fromb(h.x));
    h.y = bfb(v.y); l.y = bfb(v.y - fromb(h.y));
    h.z = bfb(v.z); l.z = bfb(v.z - fromb(h.z));
    h.w = bfb(v.w); l.w = bfb(v.w - fromb(h.w));
    ((ushort4*)inpHi)[idx] = h;
    ((ushort4*)inpLo)[idx] = l;
  } else if (bid < NSPLIT + 2048) {
    const int tb = bid - NSPLIT;
    const int zz = tb >> 10, tb2 = tb & 1023;
    const int bx = tb2 & 31, by2 = tb2 >> 5;
    const float* W = zz ? Wk : Wq;
    u16* Th = zz ? WkTh : WqTh;
    u16* Tl = zz ? WkTl : WqTl;
    const int tx = tid & 31, ty = tid >> 5;
    const int x = bx * 32 + tx;
    #pragma unroll
    for (int j = 0; j < 32; j += 8)
      t[ty + j][tx] = W[(long long)(by2 * 32 + ty + j) * DD + x];
    __syncthreads();
    const int n = by2 * 32 + tx;
    #pragma unroll
    for (int j = 0; j < 32; j += 8) {
      const int d = bx * 32 + ty + j;
      float v = t[tx][ty + j];
      u16 h = bfb(v);
      Th[(long long)d * DD + n] = h;
      Tl[(long long)d * DD + n] = bfb(v - fromb(h));
    }
  } else {
    const int lane = tid & 63, wave = tid >> 6;
    float s = 0.f;
    #pragma unroll
    for (int q = 0; q < 4; ++q) { int d = tid + q * 256; s += bq[d] * bk[d]; }
    #pragma unroll
    for (int off = 32; off; off >>= 1) s += __shfl_down(s, off);
    if (lane == 0) ws4[wave] = s;
    __syncthreads();
    if (tid == 0) c0f[0] = 0.03125f * (ws4[0] + ws4[1] + ws4[2] + ws4[3]);
  }
}

// fused pair: us = s*WqT.bk (z=0) ; vs = s*WkT.bq (z=1)
__global__ void rootv_pair(const u16* __restrict__ WqTh, const u16* __restrict__ WqTl,
                           const u16* __restrict__ WkTh, const u16* __restrict__ WkTl,
                           const float* __restrict__ bk, const float* __restrict__ bq,
                           float* __restrict__ us, float* __restrict__ vs) {
  const u16* Th = blockIdx.y ? WkTh : WqTh;
  const u16* Tl = blockIdx.y ? WkTl : WqTl;
  const float* w = blockIdx.y ? bq : bk;
  float* out = blockIdx.y ? vs : us;
  const int wave = threadIdx.x >> 6, lane = threadIdx.x & 63;
  const int row = blockIdx.x * 4 + wave;
  const u16* th = Th + (long long)row * DD;
  const u16* tl = Tl + (long long)row * DD;
  float s = 0.f;
  #pragma unroll
  for (int q = 0; q < DD / 64; ++q) {
    int d = lane + q * 64;
    s += (fromb(th[d]) + fromb(tl[d])) * w[d];
  }
  #pragma unroll
  for (int off = 32; off; off >>= 1) s += __shfl_down(s, off);
  if (lane == 0) out[row] = 0.03125f * s;
}

// Fused triple row-dot + cs zeroing: f = X.Wr + br ; spu = X.us + c0 ; spv = X.vs
__global__ void rootv3_kernel(const float* __restrict__ X, const float* __restrict__ Wr,
                              const float* __restrict__ br, const float* __restrict__ us,
                              const float* __restrict__ vs, const float* __restrict__ c0f,
                              float* __restrict__ f, float* __restrict__ spu,
                              float* __restrict__ spv, float* __restrict__ cs) {
  const int wave = threadIdx.x >> 6, lane = threadIdx.x & 63;
  const int row = blockIdx.x * 4 + wave;
  const float* r = X + (long long)row * DD;
  float s1 = 0.f, s2 = 0.f, s3 = 0.f;
  #pragma unroll
  for (int q = 0; q < DD / 64; ++q) {
    const int d = lane + q * 64;
    const float x = r[d];
    s1 = fmaf(x, Wr[d], s1);
    s2 = fmaf(x, us[d], s2);
    s3 = fmaf(x, vs[d], s3);
  }
  #pragma unroll
  for (int off = 32; off; off >>= 1) {
    s1 += __shfl_down(s1, off);
    s2 += __shfl_down(s2, off);
    s3 += __shfl_down(s3, off);
  }
  if (lane == 0) {
    f[row]   = s1 + br[0];
    spu[row] = s2 + c0f[0];
    spv[row] = s3;
    cs[row]  = 0.f;           // zero colsum accumulator for einsum atomics
  }
}

// Pre-split GEMM: C[m,n] = sum_k (Ah+Al)[m,k]*(Bh+Bl)[n,k], 3-term split-bf16 MFMA.
// EPI 0: Ch/Cl = split(acc) ; EPI 1: Cf = exp(s*acc+spu+spv) zero-diag + colsum
// partials atomically into csg ; EPI 2: Cf = acc (split-K partial).
template<int EPI>
__global__ __launch_bounds__(256) void pg_kernel(
    const u16* __restrict__ Ah, const u16* __restrict__ Al,
    const u16* __restrict__ Bh, const u16* __restrict__ Bl,
    u16* __restrict__ Ch, u16* __restrict__ Cl, float* __restrict__ Cf,
    const float* __restrict__ spu, const float* __restrict__ spv,
    float* __restrict__ csg,
    float sscale, int Kd, int Nsz, int lda,
    long long sA, long long sB, long long sC) {
  extern __shared__ char lds[];   // 2 x {Ahi,Alo,Bhi,Blo} x 8KB = 64 KB
  __shared__ float csp[2][128];   // EPI1 colsum partials (static, after dynamic)
  // XCD-aware bijective swizzle over (x,y) when wg count divisible by 8 [T1]
  int bx = blockIdx.x, by = blockIdx.y;
  {
    const int nw = gridDim.x * gridDim.y;
    if ((nw & 7) == 0) {
      int lin = by * gridDim.x + bx;
      const int cpx = nw >> 3;
      lin = (lin & 7) * cpx + (lin >> 3);
      bx = lin % gridDim.x; by = lin / gridDim.x;
    }
  }
  const int tid = threadIdx.x;
  const int m0 = bx * 128, n0 = by * 128;
  const int z = blockIdx.z;
  const u16* Abh = Ah + (long long)z * sA;
  const u16* Abl = Al + (long long)z * sA;
  const u16* Bbh = Bh + (long long)z * sB;
  const u16* Bbl = Bl + (long long)z * sB;

  const int srow = tid >> 2;            // 0..63
  const int scol = (tid & 3) * 8;       // u16 offset (16B chunk)
  const u16* a0 = Abh + (long long)(m0 + srow) * lda + scol;
  const u16* a1 = Abl + (long long)(m0 + srow) * lda + scol;
  const u16* b0 = Bbh + (long long)(n0 + srow) * lda + scol;
  const u16* b1 = Bbl + (long long)(n0 + srow) * lda + scol;
  const long long half = (long long)64 * lda;

  const int lane = tid & 63, wid = tid >> 6;
  const int wr = wid >> 1, wc = wid & 1;
  const int fr = lane & 15, fq = lane >> 4;

  f32x4 acc[4][4] = {};

  { // prologue: stage step 0 into buffer 0
    char* d = lds + tid * 16;
    gl16(a0, d);          gl16(a0 + half, d + 4096);
    gl16(a1, d + 8192);   gl16(a1 + half, d + 12288);
    gl16(b0, d + 16384);  gl16(b0 + half, d + 20480);
    gl16(b1, d + 24576);  gl16(b1 + half, d + 28672);
  }

  const int NS = Kd / 32;
  for (int s = 0; s < NS; ++s) {
    const int bb = (s & 1) << 15;
    __syncthreads();    // buf[s&1] landed; all waves' prior ds_reads drained

    if (s + 1 < NS) {   // stage next step into the other buffer (flies under MFMA)
      const int ko = (s + 1) * 32;
      char* d = lds + (((s + 1) & 1) << 15) + tid * 16;
      gl16(a0 + ko, d);          gl16(a0 + ko + half, d + 4096);
      gl16(a1 + ko, d + 8192);   gl16(a1 + ko + half, d + 12288);
      gl16(b0 + ko, d + 16384);  gl16(b0 + ko + half, d + 20480);
      gl16(b1 + ko, d + 24576);  gl16(b1 + ko + half, d + 28672);
    }

    const char* Ahs = lds + bb;
    const char* Als = lds + bb + 8192;
    const char* Bhs = lds + bb + 16384;
    const char* Bls = lds + bb + 24576;
    bf16x8 fah[4], fal[4], fbh[4], fbl[4];
    #pragma unroll
    for (int im = 0; im < 4; ++im) {
      const int off = (wr * 64 + im * 16 + fr) * 64 + fq * 16;
      fah[im] = *(const bf16x8*)(Ahs + off);
      fal[im] = *(const bf16x8*)(Als + off);
    }
    #pragma unroll
    for (int jn = 0; jn < 4; ++jn) {
      const int off = (wc * 64 + jn * 16 + fr) * 64 + fq * 16;
      fbh[jn] = *(const bf16x8*)(Bhs + off);
      fbl[jn] = *(const bf16x8*)(Bls + off);
    }
    #pragma unroll
    for (int im = 0; im < 4; ++im)
      #pragma unroll
      for (int jn = 0; jn < 4; ++jn) {
        acc[im][jn] = __builtin_amdgcn_mfma_f32_16x16x32_bf16(fah[im], fbh[jn], acc[im][jn], 0, 0, 0);
        acc[im][jn] = __builtin_amdgcn_mfma_f32_16x16x32_bf16(fah[im], fbl[jn], acc[im][jn], 0, 0, 0);
        acc[im][jn] = __builtin_amdgcn_mfma_f32_16x16x32_bf16(fal[im], fbh[jn], acc[im][jn], 0, 0, 0);
      }
  }

  // epilogue: C/D layout col=lane&15, row=(lane>>4)*4+reg  [verified rounds 3-12]
  float colp[4] = {0.f, 0.f, 0.f, 0.f};
  #pragma unroll
  for (int im = 0; im < 4; ++im) {
    #pragma unroll
    for (int jn = 0; jn < 4; ++jn) {
      const int mbase = m0 + wr * 64 + im * 16 + fq * 4;
      const int n     = n0 + wc * 64 + jn * 16 + fr;
      #pragma unroll
      for (int reg = 0; reg < 4; ++reg) {
        const int m = mbase + reg;
        const float v = acc[im][jn][reg];
        if (EPI == 0) {
          u16 h = bfb(v);
          Ch[(long long)z * sC + (long long)m * Nsz + n] = h;
          Cl[(long long)z * sC + (long long)m * Nsz + n] = bfb(v - fromb(h));
        } else if (EPI == 1) {
          float e = expf(fmaf(sscale, v, spu[z * TT + m] + spv[z * TT + n]));
          if (m == n) e = 0.f;
          colp[jn] += e;
          Cf[(long long)z * sC + (long long)m * Nsz + n] = e;
        } else {
          Cf[(long long)z * sC + (long long)m * Nsz + n] = v;
        }
      }
    }
  }
  if (EPI == 1) {
    // deterministic column reduce: shfl over fq, LDS over wr, one atomic per col
    #pragma unroll
    for (int jn = 0; jn < 4; ++jn) {
      float sSum = colp[jn];
      sSum += __shfl_down(sSum, 32);
      sSum += __shfl_down(sSum, 16);
      if (lane < 16) csp[wr][wc * 64 + jn * 16 + fr] = sSum;
    }
    __syncthreads();
    if (tid < 128)
      atomicAdd(&csg[z * TT + n0 + tid], csp[0][tid] + csp[1][tid]);
  }
}

// sum 4 split-K partials -> split bf16 hi/lo
__global__ void combine_ht(const float* __restrict__ part, u16* __restrict__ hi,
                           u16* __restrict__ lo) {
  const long long idx = (long long)blockIdx.x * 256 + threadIdx.x;  // float4 units
  const long long NQ = (long long)DD * DD / 4;
  const float4* p = (const float4*)part;
  float4 a = p[idx], b = p[idx + NQ], c = p[idx + 2 * NQ], d = p[idx + 3 * NQ];
  float vv[4] = {a.x + b.x + c.x + d.x, a.y + b.y + c.y + d.y,
                 a.z + b.z + c.z + d.z, a.w + b.w + c.w + d.w};
  ushort4 h, l;
  u16* hp = (u16*)&h; u16* lp = (u16*)&l;
  #pragma unroll
  for (int e = 0; e < 4; ++e) {
    u16 hh = bfb(vv[e]);
    hp[e] = hh; lp[e] = bfb(vv[e] - fromb(hh));
  }
  ((ushort4*)hi)[idx] = h;
  ((ushort4*)lo)[idx] = l;
}

// Laplacian build (colsum precomputed by einsum atomics): grid (BB, 4).
// L[b,0,j]=f ; L[b,i,j] = -A + (i==j)*cs
__global__ __launch_bounds__(256) void csbl_kernel(
    const float* __restrict__ Aall, const float* __restrict__ f,
    const float* __restrict__ cs, float* __restrict__ L) {
  const int b = blockIdx.x, jq = blockIdx.y * 64;
  const float* Ab = Aall + (long long)b * TT * TT;
  float* Lb = L + (long long)b * TT * TT;
  const int tid = threadIdx.x;
  for (int e = tid; e < TT * 64; e += 256) {
    const int i = e >> 6, j = jq + (e & 63);
    float v;
    if (i == 0) v = f[b * TT + j];
    else {
      v = -Ab[(long long)i * TT + j];
      if (i == j) v += cs[b * TT + j];
    }
    Lb[(long long)i * TT + j] = v;
  }
}

// 32x32 Gauss-Jordan inverse in one wave's registers. Round-13: pivot-row
// broadcast via v_readlane (uniform source lane per half-wave, s unrolled ->
// compile-time lane) instead of ds_bpermute — same values, no LDS round-trip.
// Only colv (per-lane source) keeps __shfl.
template<bool ZLAST>
__device__ __forceinline__ void gj32(float* d, int rl, int h) {
  #pragma unroll
  for (int s = 0; s < 32; ++s) {
    const int t = ZLAST ? ((s + 1) & 31) : s;
    const int tl = t & 15, th = t >> 4;
    float rowv[16];
    #pragma unroll
    for (int j = 0; j < 16; ++j) {
      const float a0 = rdlane(d[j], t);        // row t, col j      (h=0 view)
      const float a1 = rdlane(d[j], t + 32);   // row t, col 16+j   (h=1 view)
      rowv[j] = h ? a1 : a0;
    }
    const float pv = th ? rdlane(d[tl], t + 32) : rdlane(d[tl], t);  // M[t][t]
    const float colv = __shfl(d[tl], rl + 32 * th);                  // M[rl][t]
    const float ip = 1.0f / pv;
    if (rl == t) {
      #pragma unroll
      for (int j = 0; j < 16; ++j) {
        float v = rowv[j] * ip;
        if (j == tl) v = (h == th) ? ip : v;
        d[j] = v;
      }
    } else {
      const float cip = colv * ip;
      #pragma unroll
      for (int j = 0; j < 16; ++j) {
        float v = fmaf(-cip, rowv[j], d[j]);
        if (j == tl) v = (h == th) ? -cip : v;
        d[j] = v;
      }
    }
  }
}

// Single-block-per-matrix blocked Gauss-Jordan, 512 threads (round-12 verified
// structure: ping-pong RT staging from step-4 registers, C prefetch under gj32).
#define G3_RAH 0        // u16 [256][40]  RT buffer A hi
#define G3_RAL 20480
#define G3_RBH 40960    // u16 [256][40]  RT buffer B hi
#define G3_RBL 61440
#define G3_DH  81920    // u16 [32][40]
#define G3_DL  84480
#define G3_LDS 87040
__global__ __launch_bounds__(512, 2) void gj_single(float* __restrict__ Mg) {
  extern __shared__ char lds[];
  u16* Dh = (u16*)(lds + G3_DH);
  u16* Dl = (u16*)(lds + G3_DL);
  float* M = Mg + (long long)blockIdx.x * TT * TT;
  const int tid = threadIdx.x, wid = tid >> 6, lane = tid & 63;
  const int fr = lane & 15, fq = lane >> 4;

  u16* curh = (u16*)(lds + G3_RAH);
  u16* curl = (u16*)(lds + G3_RAL);
  u16* nxth = (u16*)(lds + G3_RBH);
  u16* nxtl = (u16*)(lds + G3_RBL);

  // initial staging for first panel (p=1, rows 32..63) into cur
  {
    const int sr = tid & 31, cb = (tid >> 5) * 16;
    const float4* src = (const float4*)(M + (long long)(NB + sr) * TT + cb);
    #pragma unroll
    for (int q = 0; q < 4; ++q) {
      float4 v = src[q];
      float vv[4] = {v.x, v.y, v.z, v.w};
      #pragma unroll
      for (int l = 0; l < 4; ++l) {
        const int j = cb + q * 4 + l;
        u16 h = bfb(vv[l]);
        curh[j * 40 + sr] = h;
        curl[j * 40 + sr] = bfb(vv[l] - fromb(h));
      }
    }
  }
  __syncthreads();

  for (int pi = 0; pi < 8; ++pi) {
    const int p = (pi + 1) & 7;       // panels 1..7 then 0
    const int P0 = p * NB;
    const int P0n = ((pi + 2) & 7) * NB;   // next panel's row base (unused at pi==7)

    // ---- C prefetch for both step-4 chunks (flies under gj32)
    float4 c0a, c0b, c1a, c1b;
    {
      const float4* cp0 = (const float4*)(M + (long long)(wid * 16 + fr) * TT + P0 + fq * 8);
      const float4* cp1 = (const float4*)(M + (long long)(128 + wid * 16 + fr) * TT + P0 + fq * 8);
      c0a = cp0[0]; c0b = cp0[1];
      c1a = cp1[0]; c1b = cp1[1];
    }

    // ---- step 2: wave 0 computes Dinv from cur
    if (wid == 0) {
      const int rl = lane & 31, h2 = lane >> 5;
      float d[16];
      #pragma unroll
      for (int j = 0; j < 16; ++j) {
        const int col = P0 + h2 * 16 + j;
        d[j] = fromb(curh[col * 40 + rl]) + fromb(curl[col * 40 + rl]);
      }
      if (p == 0) gj32<true>(d, rl, h2); else gj32<false>(d, rl, h2);
      #pragma unroll
      for (int j = 0; j < 16; ++j) {
        u16 hh = bfb(d[j]);
        Dh[rl * 40 + h2 * 16 + j] = hh;
        Dl[rl * 40 + h2 * 16 + j] = bfb(d[j] - fromb(hh));
      }
    }
    __syncthreads();

    // ---- step 3: Rp = Dinv @ R, in-place into cur; write M pivot rows.
    #pragma unroll
    for (int cf = 0; cf < 2; ++cf) {
      const int j = wid * 32 + cf * 16 + fr;
      const bf16x8 bh = *(const bf16x8*)&curh[j * 40 + fq * 8];
      const bf16x8 bl = *(const bf16x8*)&curl[j * 40 + fq * 8];
      const bool inP = ((unsigned)(j - P0)) < 32u;
      const int s = j - P0;
      f32x4 acc2[2];
      #pragma unroll
      for (int fi = 0; fi < 2; ++fi) {
        const bf16x8 ah = *(const bf16x8*)&Dh[(fi * 16 + fr) * 40 + fq * 8];
        const bf16x8 al = *(const bf16x8*)&Dl[(fi * 16 + fr) * 40 + fq * 8];
        f32x4 a = {};
        a = __builtin_amdgcn_mfma_f32_16x16x32_bf16(ah, bh, a, 0, 0, 0);
        a = __builtin_amdgcn_mfma_f32_16x16x32_bf16(ah, bl, a, 0, 0, 0);
        a = __builtin_amdgcn_mfma_f32_16x16x32_bf16(al, bh, a, 0, 0, 0);
        acc2[fi] = a;
      }
      #pragma unroll
      for (int fi = 0; fi < 2; ++fi) {
        ushort4 oh, ol;
        u16* hp = (u16*)&oh; u16* lp = (u16*)&ol;
        float mvals[4];
        #pragma unroll
        for (int reg = 0; reg < 4; ++reg) {
          const int t = fi * 16 + fq * 4 + reg;
          float v = acc2[fi][reg];
          if (inP) v = fromb(Dh[t * 40 + s]) + fromb(Dl[t * 40 + s]);  // exact Dinv
          mvals[reg] = v;
          float rv = inP ? (v + ((t == s) ? 1.0f : 0.0f)) : v;  // staging: Dinv+I
          u16 hh = bfb(rv);
          hp[reg] = hh;
          lp[reg] = bfb(rv - fromb(hh));
        }
        *(ushort4*)&curh[j * 40 + fi * 16 + fq * 4] = oh;
        *(ushort4*)&curl[j * 40 + fi * 16 + fq * 4] = ol;
        #pragma unroll
        for (int reg = 0; reg < 4; ++reg)
          M[(long long)(P0 + fi * 16 + fq * 4 + reg) * TT + j] = mvals[reg];
      }
    }
    __syncthreads();   // cur holds RpB^T for ALL columns

    // ---- step 4: rank-32 update, 2 unrolled chunks of 128 rows.
    #pragma unroll
    for (int ch = 0; ch < 2; ++ch) {
      const int r0 = ch * 128 + wid * 16;
      const float4 ca = ch ? c1a : c0a;
      const float4 cb2 = ch ? c1b : c0b;
      bf16x8 ah, al;
      {
        float cv[8] = {ca.x, ca.y, ca.z, ca.w, cb2.x, cb2.y, cb2.z, cb2.w};
        u16 hbuf[8], lbuf[8];
        #pragma unroll
        for (int e = 0; e < 8; ++e) {
          float x = -cv[e];
          u16 h = bfb(x);
          hbuf[e] = h; lbuf[e] = bfb(x - fromb(h));
        }
        ah = *(const bf16x8*)hbuf;
        al = *(const bf16x8*)lbuf;
      }
      f32x4 acc[16];
      #pragma unroll
      for (int cf = 0; cf < 16; ++cf) {
        const int j = cf * 16 + fr;
        const bf16x8 bh = *(const bf16x8*)&curh[j * 40 + fq * 8];
        const bf16x8 bl = *(const bf16x8*)&curl[j * 40 + fq * 8];
        f32x4 a = {};
        a = __builtin_amdgcn_mfma_f32_16x16x32_bf16(ah, bh, a, 0, 0, 0);
        a = __builtin_amdgcn_mfma_f32_16x16x32_bf16(ah, bl, a, 0, 0, 0);
        a = __builtin_amdgcn_mfma_f32_16x16x32_bf16(al, bh, a, 0, 0, 0);
        acc[cf] = a;
      }
      #pragma unroll
      for (int reg = 0; reg < 4; ++reg) {
        const int m = r0 + fq * 4 + reg;
        if ((unsigned)(m - P0) < 32u) continue;   // pivot rows done in step 3
        float* Mrow = M + (long long)m * TT + fr;
        float mv[16];
        #pragma unroll
        for (int cf = 0; cf < 16; ++cf) mv[cf] = Mrow[cf * 16];
        #pragma unroll
        for (int cf = 0; cf < 16; ++cf) mv[cf] += acc[cf][reg];
        #pragma unroll
        for (int cf = 0; cf < 16; ++cf) Mrow[cf * 16] = mv[cf];
        // export next panel's R rows (replaces staging; same fp32 values)
        if (pi < 7 && (unsigned)(m - P0n) < 32u) {
          const int t = m - P0n;
          #pragma unroll
          for (int cf = 0; cf < 16; ++cf) {
            const int j = cf * 16 + fr;
            u16 hh = bfb(mv[cf]);
            nxth[j * 40 + t] = hh;
            nxtl[j * 40 + t] = bfb(mv[cf] - fromb(hh));
          }
        }
      }
    }
    __syncthreads();   // M + nxt ready before next panel

    // ping-pong RT buffers
    u16* th_ = curh; curh = nxth; nxth = th_;
    u16* tl_ = curl; curl = nxtl; nxtl = tl_;
  }
}

// Tiled output epilogue (verified round 10): 64x64 tiles, LDS transpose,
// coalesced A and Linv^T access.
__global__ __launch_bounds__(256) void out_tile_kernel(
    const float* __restrict__ Aall, const float* __restrict__ Linv,
    const float* __restrict__ f, float* __restrict__ out) {
  __shared__ float As[64][65];
  __shared__ float Ls[64][65];
  __shared__ float dg[64], l0v[64], fv[64];
  const int b = blockIdx.x, i0 = blockIdx.y * 64, j0 = blockIdx.z * 64;
  const float* Ab = Aall + (long long)b * TT * TT;
  const float* Lb = Linv + (long long)b * TT * TT;
  const int tid = threadIdx.x;
  #pragma unroll
  for (int q = 0; q < 16; ++q) {
    int idx = q * 256 + tid;
    int ii = idx >> 6, jj = idx & 63;
    As[ii][jj] = Ab[(long long)(i0 + ii) * TT + j0 + jj];      // A[i][j], j fast
    Ls[ii][jj] = Lb[(long long)(j0 + ii) * TT + i0 + jj];      // Linv[j][i], i fast
  }
  if (tid < 64) {
    dg[tid]  = Lb[(long long)(j0 + tid) * TT + j0 + tid];
    l0v[tid] = Lb[(long long)(j0 + tid) * TT];
    fv[tid]  = f[b * TT + j0 + tid];
  }
  __syncthreads();
  #pragma unroll
  for (int q = 0; q < 16; ++q) {
    int idx = q * 256 + tid;
    int jj = idx >> 6, ii = idx & 63;                           // ii fast -> coalesced write
    int i = i0 + ii, j = j0 + jj;
    float t1 = (j > 0) ? dg[jj] : 0.f;
    float t2 = (i > 0) ? Ls[jj][ii] : 0.f;
    out[(long long)(b * TT + j) * (TT + 1) + i + 1] = As[ii][jj] * (t1 - t2);
  }
  if (i0 == 0 && tid < 64) {
    int j = j0 + tid;
    out[(long long)(b * TT + j) * (TT + 1)] = fv[tid] * l0v[tid];
  }
}

extern "C" void kernel_launch(void* const* d_in, const int* in_sizes, int n_in,
                              void* d_out, int out_size, void* d_ws, size_t ws_size,
                              hipStream_t stream) {
  const float* inp = (const float*)d_in[0];
  const float* Wk  = (const float*)d_in[1];
  const float* bk  = (const float*)d_in[2];
  const float* Wq  = (const float*)d_in[3];
  const float* bq  = (const float*)d_in[4];
  const float* Wr  = (const float*)d_in[5];
  const float* br  = (const float*)d_in[6];
  float* out = (float*)d_out;

  // workspace layout (~114 MiB peak; 126 MiB proven available round 1)
  const long long NI = (long long)BB * TT * DD;   // 12,582,912
  u16* inpHi = (u16*)d_ws;
  u16* inpLo = inpHi + NI;
  u16* Zhi   = inpLo + NI;
  u16* Zlo   = Zhi + NI;
  u16* HTh   = Zlo + NI;
  u16* HTl   = HTh + (long long)DD * DD;
  u16* WqTh  = HTl + (long long)DD * DD;          // region later reused by A_
  u16* WqTl  = WqTh + (long long)DD * DD;
  u16* WkTh  = WqTl + (long long)DD * DD;
  u16* WkTl  = WkTh + (long long)DD * DD;
  float* A_  = (float*)WqTh;                      // aliases WqT/WkT (dead by einsum)
  float* f   = A_ + (long long)BB * TT * TT;
  float* cs  = f + BB * TT;
  float* us  = cs + BB * TT;
  float* vs_ = us + DD;
  float* spu = vs_ + DD;
  float* spv = spu + BB * TT;
  float* c0f = spv + BB * TT;
  // Z region reused: HT split-K partials (before Z), then L (after einsum)
  float* HTpart = (float*)Zhi;                    // 4 x DD x DD f32 = 16 MB
  float* L   = (float*)Zhi;

  (void)hipFuncSetAttribute(reinterpret_cast<const void*>(&pg_kernel<0>),
                            hipFuncAttributeMaxDynamicSharedMemorySize, 65536);
  (void)hipFuncSetAttribute(reinterpret_cast<const void*>(&pg_kernel<1>),
                            hipFuncAttributeMaxDynamicSharedMemorySize, 65536);
  (void)hipFuncSetAttribute(reinterpret_cast<const void*>(&pg_kernel<2>),
                            hipFuncAttributeMaxDynamicSharedMemorySize, 65536);
  (void)hipFuncSetAttribute(reinterpret_cast<const void*>(&gj_single),
                            hipFuncAttributeMaxDynamicSharedMemorySize, G3_LDS);

  const float s = 0.03125f;
  const int M = BB * TT;  // 12288

  // 1. fused prep: split(inp) + transpose+split(Wq,Wk) + c0
  prep_kernel<<<NSPLIT + 2048 + 1, 256, 0, stream>>>(
      inp, Wq, Wk, bq, bk, inpHi, inpLo, WqTh, WqTl, WkTh, WkTl, c0f);

  // 2. us = s*WqT.bk ; vs = s*WkT.bq  (one fused launch)
  rootv_pair<<<dim3(DD / 4, 2), 256, 0, stream>>>(WqTh, WqTl, WkTh, WkTl, bk, bq, us, vs_);

  // 3. HT[e,d] = sum_n Wk[n,e]*Wq[n,d] via split-K (4 partials) + combine
  pg_kernel<2><<<dim3(8, 8, 4), 256, 65536, stream>>>(
      WkTh, WkTl, WqTh, WqTl, nullptr, nullptr, HTpart, nullptr, nullptr, nullptr,
      0.f, 256, DD, DD, 256, 256, (long long)DD * DD);
  combine_ht<<<DD * DD / 4 / 256, 256, 0, stream>>>(HTpart, HTh, HTl);

  // 4. Z = X @ H  (overwrites HTpart region — stream-ordered after combine)
  pg_kernel<0><<<dim3(M / 128, DD / 128, 1), 256, 65536, stream>>>(
      inpHi, inpLo, HTh, HTl, Zhi, Zlo, nullptr, nullptr, nullptr, nullptr,
      0.f, DD, DD, DD, 0, 0, 0);

  // 5. fused row dots: f = X.Wr+br ; spu = X.us+c0 ; spv = X.vs ; cs = 0
  rootv3_kernel<<<M / 4, 256, 0, stream>>>(inp, Wr, br, us, vs_, c0f, f, spu, spv, cs);

  // 6. A[b,t,s] = (t==s)?0:exp(s*(z_t.x_s)+spu+spv), + colsum atomics into cs
  pg_kernel<1><<<dim3(TT / 128, TT / 128, BB), 256, 65536, stream>>>(
      Zhi, Zlo, inpHi, inpLo, nullptr, nullptr, A_, spu, spv, cs,
      s, DD, TT, DD, (long long)TT * DD, (long long)TT * DD, (long long)TT * TT);

  // 7. Laplacian build (colsum already in cs)
  csbl_kernel<<<dim3(BB, 4), 256, 0, stream>>>(A_, f, cs, L);

  // 8. single-block-per-matrix blocked Gauss-Jordan (panels 1..7 then 0)
  gj_single<<<BB, 512, G3_LDS, stream>>>(L);

  // 9. tiled output epilogue (coalesced A and Linv^T access)
  out_tile_kernel<<<dim3(BB, 4, 4), 256, 0, stream>>>(A_, L, f, out);
}

// Round 14
// 319.819 us; speedup vs baseline: 1.0558x; 1.0558x over previous
//
#include <hip/hip_runtime.h>
#include <hip/hip_bf16.h>
#include <math.h>

#define BB 48
#define TT 256
#define DD 1024
#define NB 32

typedef __attribute__((ext_vector_type(8))) short bf16x8;
typedef __attribute__((ext_vector_type(4))) float f32x4;
typedef unsigned short u16;

__device__ __forceinline__ u16 bfb(float x) {
  __hip_bfloat16 h = __float2bfloat16(x);   // RNE
  return __builtin_bit_cast(u16, h);
}
__device__ __forceinline__ float fromb(u16 u) {
  unsigned v = (unsigned)u << 16;
  return __builtin_bit_cast(float, v);
}
__device__ __forceinline__ void gl16(const void* g, void* l) {
  __builtin_amdgcn_global_load_lds((const __attribute__((address_space(1))) unsigned int*)g,
                                   (__attribute__((address_space(3))) unsigned int*)l, 16, 0, 0);
}

// Fused prep: [0,NSPLIT) split(inp); [NSPLIT,NSPLIT+2048) transpose+split W;
// last block: c0 = s*bq.bk. Each block takes exactly one role (block-uniform).
#define NSPLIT 12288
__global__ __launch_bounds__(256) void prep_kernel(
    const float* __restrict__ inp, const float* __restrict__ Wq, const float* __restrict__ Wk,
    const float* __restrict__ bq, const float* __restrict__ bk,
    u16* __restrict__ inpHi, u16* __restrict__ inpLo,
    u16* __restrict__ WqTh, u16* __restrict__ WqTl,
    u16* __restrict__ WkTh, u16* __restrict__ WkTl,
    float* __restrict__ c0f) {
  __shared__ float t[32][33];
  __shared__ float ws4[4];
  const int bid = blockIdx.x, tid = threadIdx.x;
  if (bid < NSPLIT) {
    const int idx = bid * 256 + tid;
    float4 v = ((const float4*)inp)[idx];
    ushort4 h, l;
    h.x = bfb(v.x); l.x = bfb(v.x - fromb(h.x));
    h.y = bfb(v.y); l.y = bfb(v.y - fromb(h.y));
    h.z = bfb(v.z); l.z = bfb(v.z - fromb(h.z));
    h.w = bfb(v.w); l.w = bfb(v.w - fromb(h.w));
    ((ushort4*)inpHi)[idx] = h;
    ((ushort4*)inpLo)[idx] = l;
  } else if (bid < NSPLIT + 2048) {
    const int tb = bid - NSPLIT;
    const int zz = tb >> 10, tb2 = tb & 1023;
    const int bx = tb2 & 31, by2 = tb2 >> 5;
    const float* W = zz ? Wk : Wq;
    u16* Th = zz ? WkTh : WqTh;
    u16* Tl = zz ? WkTl : WqTl;
    const int tx = tid & 31, ty = tid >> 5;
    const int x = bx * 32 + tx;
    #pragma unroll
    for (int j = 0; j < 32; j += 8)
      t[ty + j][tx] = W[(long long)(by2 * 32 + ty + j) * DD + x];
    __syncthreads();
    const int n = by2 * 32 + tx;
    #pragma unroll
    for (int j = 0; j < 32; j += 8) {
      const int d = bx * 32 + ty + j;
      float v = t[tx][ty + j];
      u16 h = bfb(v);
      Th[(long long)d * DD + n] = h;
      Tl[(long long)d * DD + n] = bfb(v - fromb(h));
    }
  } else {
    const int lane = tid & 63, wave = tid >> 6;
    float s = 0.f;
    #pragma unroll
    for (int q = 0; q < 4; ++q) { int d = tid + q * 256; s += bq[d] * bk[d]; }
    #pragma unroll
    for (int off = 32; off; off >>= 1) s += __shfl_down(s, off);
    if (lane == 0) ws4[wave] = s;
    __syncthreads();
    if (tid == 0) c0f[0] = 0.03125f * (ws4[0] + ws4[1] + ws4[2] + ws4[3]);
  }
}

// fused pair: us = s*WqT.bk (z=0) ; vs = s*WkT.bq (z=1)
__global__ void rootv_pair(const u16* __restrict__ WqTh, const u16* __restrict__ WqTl,
                           const u16* __restrict__ WkTh, const u16* __restrict__ WkTl,
                           const float* __restrict__ bk, const float* __restrict__ bq,
                           float* __restrict__ us, float* __restrict__ vs) {
  const u16* Th = blockIdx.y ? WkTh : WqTh;
  const u16* Tl = blockIdx.y ? WkTl : WqTl;
  const float* w = blockIdx.y ? bq : bk;
  float* out = blockIdx.y ? vs : us;
  const int wave = threadIdx.x >> 6, lane = threadIdx.x & 63;
  const int row = blockIdx.x * 4 + wave;
  const u16* th = Th + (long long)row * DD;
  const u16* tl = Tl + (long long)row * DD;
  float s = 0.f;
  #pragma unroll
  for (int q = 0; q < DD / 64; ++q) {
    int d = lane + q * 64;
    s += (fromb(th[d]) + fromb(tl[d])) * w[d];
  }
  #pragma unroll
  for (int off = 32; off; off >>= 1) s += __shfl_down(s, off);
  if (lane == 0) out[row] = 0.03125f * s;
}

// Fused triple row-dot + cs zeroing: f = X.Wr + br ; spu = X.us + c0 ; spv = X.vs
__global__ void rootv3_kernel(const float* __restrict__ X, const float* __restrict__ Wr,
                              const float* __restrict__ br, const float* __restrict__ us,
                              const float* __restrict__ vs, const float* __restrict__ c0f,
                              float* __restrict__ f, float* __restrict__ spu,
                              float* __restrict__ spv, float* __restrict__ cs) {
  const int wave = threadIdx.x >> 6, lane = threadIdx.x & 63;
  const int row = blockIdx.x * 4 + wave;
  const float* r = X + (long long)row * DD;
  float s1 = 0.f, s2 = 0.f, s3 = 0.f;
  #pragma unroll
  for (int q = 0; q < DD / 64; ++q) {
    const int d = lane + q * 64;
    const float x = r[d];
    s1 = fmaf(x, Wr[d], s1);
    s2 = fmaf(x, us[d], s2);
    s3 = fmaf(x, vs[d], s3);
  }
  #pragma unroll
  for (int off = 32; off; off >>= 1) {
    s1 += __shfl_down(s1, off);
    s2 += __shfl_down(s2, off);
    s3 += __shfl_down(s3, off);
  }
  if (lane == 0) {
    f[row]   = s1 + br[0];
    spu[row] = s2 + c0f[0];
    spv[row] = s3;
    cs[row]  = 0.f;           // zero colsum accumulator for einsum atomics
  }
}

// Pre-split GEMM: C[m,n] = sum_k (Ah+Al)[m,k]*(Bh+Bl)[n,k], 3-term split-bf16 MFMA.
// EPI 0: Ch/Cl = split(acc) ; EPI 1: Cf = exp(s*acc+spu+spv) zero-diag + colsum
// partials atomically into csg ; EPI 2: Cf = acc (split-K partial).
template<int EPI>
__global__ __launch_bounds__(256) void pg_kernel(
    const u16* __restrict__ Ah, const u16* __restrict__ Al,
    const u16* __restrict__ Bh, const u16* __restrict__ Bl,
    u16* __restrict__ Ch, u16* __restrict__ Cl, float* __restrict__ Cf,
    const float* __restrict__ spu, const float* __restrict__ spv,
    float* __restrict__ csg,
    float sscale, int Kd, int Nsz, int lda,
    long long sA, long long sB, long long sC) {
  extern __shared__ char lds[];   // 2 x {Ahi,Alo,Bhi,Blo} x 8KB = 64 KB
  __shared__ float csp[2][128];   // EPI1 colsum partials (static, after dynamic)
  // XCD-aware bijective swizzle over (x,y) when wg count divisible by 8 [T1]
  int bx = blockIdx.x, by = blockIdx.y;
  {
    const int nw = gridDim.x * gridDim.y;
    if ((nw & 7) == 0) {
      int lin = by * gridDim.x + bx;
      const int cpx = nw >> 3;
      lin = (lin & 7) * cpx + (lin >> 3);
      bx = lin % gridDim.x; by = lin / gridDim.x;
    }
  }
  const int tid = threadIdx.x;
  const int m0 = bx * 128, n0 = by * 128;
  const int z = blockIdx.z;
  const u16* Abh = Ah + (long long)z * sA;
  const u16* Abl = Al + (long long)z * sA;
  const u16* Bbh = Bh + (long long)z * sB;
  const u16* Bbl = Bl + (long long)z * sB;

  const int srow = tid >> 2;            // 0..63
  const int scol = (tid & 3) * 8;       // u16 offset (16B chunk)
  const u16* a0 = Abh + (long long)(m0 + srow) * lda + scol;
  const u16* a1 = Abl + (long long)(m0 + srow) * lda + scol;
  const u16* b0 = Bbh + (long long)(n0 + srow) * lda + scol;
  const u16* b1 = Bbl + (long long)(n0 + srow) * lda + scol;
  const long long half = (long long)64 * lda;

  const int lane = tid & 63, wid = tid >> 6;
  const int wr = wid >> 1, wc = wid & 1;
  const int fr = lane & 15, fq = lane >> 4;

  f32x4 acc[4][4] = {};

  { // prologue: stage step 0 into buffer 0
    char* d = lds + tid * 16;
    gl16(a0, d);          gl16(a0 + half, d + 4096);
    gl16(a1, d + 8192);   gl16(a1 + half, d + 12288);
    gl16(b0, d + 16384);  gl16(b0 + half, d + 20480);
    gl16(b1, d + 24576);  gl16(b1 + half, d + 28672);
  }

  const int NS = Kd / 32;
  for (int s = 0; s < NS; ++s) {
    const int bb = (s & 1) << 15;
    __syncthreads();    // buf[s&1] landed; all waves' prior ds_reads drained

    if (s + 1 < NS) {   // stage next step into the other buffer (flies under MFMA)
      const int ko = (s + 1) * 32;
      char* d = lds + (((s + 1) & 1) << 15) + tid * 16;
      gl16(a0 + ko, d);          gl16(a0 + ko + half, d + 4096);
      gl16(a1 + ko, d + 8192);   gl16(a1 + ko + half, d + 12288);
      gl16(b0 + ko, d + 16384);  gl16(b0 + ko + half, d + 20480);
      gl16(b1 + ko, d + 24576);  gl16(b1 + ko + half, d + 28672);
    }

    const char* Ahs = lds + bb;
    const char* Als = lds + bb + 8192;
    const char* Bhs = lds + bb + 16384;
    const char* Bls = lds + bb + 24576;
    bf16x8 fah[4], fal[4], fbh[4], fbl[4];
    #pragma unroll
    for (int im = 0; im < 4; ++im) {
      const int off = (wr * 64 + im * 16 + fr) * 64 + fq * 16;
      fah[im] = *(const bf16x8*)(Ahs + off);
      fal[im] = *(const bf16x8*)(Als + off);
    }
    #pragma unroll
    for (int jn = 0; jn < 4; ++jn) {
      const int off = (wc * 64 + jn * 16 + fr) * 64 + fq * 16;
      fbh[jn] = *(const bf16x8*)(Bhs + off);
      fbl[jn] = *(const bf16x8*)(Bls + off);
    }
    #pragma unroll
    for (int im = 0; im < 4; ++im)
      #pragma unroll
      for (int jn = 0; jn < 4; ++jn) {
        acc[im][jn] = __builtin_amdgcn_mfma_f32_16x16x32_bf16(fah[im], fbh[jn], acc[im][jn], 0, 0, 0);
        acc[im][jn] = __builtin_amdgcn_mfma_f32_16x16x32_bf16(fah[im], fbl[jn], acc[im][jn], 0, 0, 0);
        acc[im][jn] = __builtin_amdgcn_mfma_f32_16x16x32_bf16(fal[im], fbh[jn], acc[im][jn], 0, 0, 0);
      }
  }

  // epilogue: C/D layout col=lane&15, row=(lane>>4)*4+reg  [verified rounds 3-13]
  float colp[4] = {0.f, 0.f, 0.f, 0.f};
  #pragma unroll
  for (int im = 0; im < 4; ++im) {
    #pragma unroll
    for (int jn = 0; jn < 4; ++jn) {
      const int mbase = m0 + wr * 64 + im * 16 + fq * 4;
      const int n     = n0 + wc * 64 + jn * 16 + fr;
      #pragma unroll
      for (int reg = 0; reg < 4; ++reg) {
        const int m = mbase + reg;
        const float v = acc[im][jn][reg];
        if (EPI == 0) {
          u16 h = bfb(v);
          Ch[(long long)z * sC + (long long)m * Nsz + n] = h;
          Cl[(long long)z * sC + (long long)m * Nsz + n] = bfb(v - fromb(h));
        } else if (EPI == 1) {
          float e = expf(fmaf(sscale, v, spu[z * TT + m] + spv[z * TT + n]));
          if (m == n) e = 0.f;
          colp[jn] += e;
          Cf[(long long)z * sC + (long long)m * Nsz + n] = e;
        } else {
          Cf[(long long)z * sC + (long long)m * Nsz + n] = v;
        }
      }
    }
  }
  if (EPI == 1) {
    // deterministic column reduce: shfl over fq, LDS over wr, one atomic per col
    #pragma unroll
    for (int jn = 0; jn < 4; ++jn) {
      float sSum = colp[jn];
      sSum += __shfl_down(sSum, 32);
      sSum += __shfl_down(sSum, 16);
      if (lane < 16) csp[wr][wc * 64 + jn * 16 + fr] = sSum;
    }
    __syncthreads();
    if (tid < 128)
      atomicAdd(&csg[z * TT + n0 + tid], csp[0][tid] + csp[1][tid]);
  }
}

// sum 4 split-K partials -> split bf16 hi/lo
__global__ void combine_ht(const float* __restrict__ part, u16* __restrict__ hi,
                           u16* __restrict__ lo) {
  const long long idx = (long long)blockIdx.x * 256 + threadIdx.x;  // float4 units
  const long long NQ = (long long)DD * DD / 4;
  const float4* p = (const float4*)part;
  float4 a = p[idx], b = p[idx + NQ], c = p[idx + 2 * NQ], d = p[idx + 3 * NQ];
  float vv[4] = {a.x + b.x + c.x + d.x, a.y + b.y + c.y + d.y,
                 a.z + b.z + c.z + d.z, a.w + b.w + c.w + d.w};
  ushort4 h, l;
  u16* hp = (u16*)&h; u16* lp = (u16*)&l;
  #pragma unroll
  for (int e = 0; e < 4; ++e) {
    u16 hh = bfb(vv[e]);
    hp[e] = hh; lp[e] = bfb(vv[e] - fromb(hh));
  }
  ((ushort4*)hi)[idx] = h;
  ((ushort4*)lo)[idx] = l;
}

// Laplacian build (colsum precomputed by einsum atomics): grid (BB, 4).
__global__ __launch_bounds__(256) void csbl_kernel(
    const float* __restrict__ Aall, const float* __restrict__ f,
    const float* __restrict__ cs, float* __restrict__ L) {
  const int b = blockIdx.x, jq = blockIdx.y * 64;
  const float* Ab = Aall + (long long)b * TT * TT;
  float* Lb = L + (long long)b * TT * TT;
  const int tid = threadIdx.x;
  for (int e = tid; e < TT * 64; e += 256) {
    const int i = e >> 6, j = jq + (e & 63);
    float v;
    if (i == 0) v = f[b * TT + j];
    else {
      v = -Ab[(long long)i * TT + j];
      if (i == j) v += cs[b * TT + j];
    }
    Lb[(long long)i * TT + j] = v;
  }
}

// 32x32 Gauss-Jordan inverse in one wave's registers — ROUND-12 VERIFIED
// __shfl version (round-13's readlane variant regressed: 32 serial readlanes
// + selects > 16 bpermutes; reverted).
template<bool ZLAST>
__device__ __forceinline__ void gj32(float* d, int rl, int h) {
  #pragma unroll
  for (int s = 0; s < 32; ++s) {
    const int t = ZLAST ? ((s + 1) & 31) : s;
    const int tl = t & 15, th = t >> 4;
    float rowv[16];
    #pragma unroll
    for (int j = 0; j < 16; ++j) rowv[j] = __shfl(d[j], t + 32 * h);
    const float pv   = __shfl(d[tl], t + 32 * th);
    const float colv = __shfl(d[tl], rl + 32 * th);
    const float ip = 1.0f / pv;
    if (rl == t) {
      #pragma unroll
      for (int j = 0; j < 16; ++j) {
        float v = rowv[j] * ip;
        if (j == tl) v = (h == th) ? ip : v;
        d[j] = v;
      }
    } else {
      const float cip = colv * ip;
      #pragma unroll
      for (int j = 0; j < 16; ++j) {
        float v = fmaf(-cip, rowv[j], d[j]);
        if (j == tl) v = (h == th) ? -cip : v;
        d[j] = v;
      }
    }
  }
}

// Single-block-per-matrix blocked Gauss-Jordan, 512 threads (round-12 verified
// structure: ping-pong RT staging from step-4 registers, C prefetch under gj32).
#define G3_RAH 0        // u16 [256][40]  RT buffer A hi
#define G3_RAL 20480
#define G3_RBH 40960    // u16 [256][40]  RT buffer B hi
#define G3_RBL 61440
#define G3_DH  81920    // u16 [32][40]
#define G3_DL  84480
#define G3_LDS 87040
__global__ __launch_bounds__(512, 2) void gj_single(float* __restrict__ Mg) {
  extern __shared__ char lds[];
  u16* Dh = (u16*)(lds + G3_DH);
  u16* Dl = (u16*)(lds + G3_DL);
  float* M = Mg + (long long)blockIdx.x * TT * TT;
  const int tid = threadIdx.x, wid = tid >> 6, lane = tid & 63;
  const int fr = lane & 15, fq = lane >> 4;

  u16* curh = (u16*)(lds + G3_RAH);
  u16* curl = (u16*)(lds + G3_RAL);
  u16* nxth = (u16*)(lds + G3_RBH);
  u16* nxtl = (u16*)(lds + G3_RBL);

  // initial staging for first panel (p=1, rows 32..63) into cur
  {
    const int sr = tid & 31, cb = (tid >> 5) * 16;
    const float4* src = (const float4*)(M + (long long)(NB + sr) * TT + cb);
    #pragma unroll
    for (int q = 0; q < 4; ++q) {
      float4 v = src[q];
      float vv[4] = {v.x, v.y, v.z, v.w};
      #pragma unroll
      for (int l = 0; l < 4; ++l) {
        const int j = cb + q * 4 + l;
        u16 h = bfb(vv[l]);
        curh[j * 40 + sr] = h;
        curl[j * 40 + sr] = bfb(vv[l] - fromb(h));
      }
    }
  }
  __syncthreads();

  for (int pi = 0; pi < 8; ++pi) {
    const int p = (pi + 1) & 7;       // panels 1..7 then 0
    const int P0 = p * NB;
    const int P0n = ((pi + 2) & 7) * NB;   // next panel's row base (unused at pi==7)

    // ---- C prefetch for both step-4 chunks (flies under gj32)
    float4 c0a, c0b, c1a, c1b;
    {
      const float4* cp0 = (const float4*)(M + (long long)(wid * 16 + fr) * TT + P0 + fq * 8);
      const float4* cp1 = (const float4*)(M + (long long)(128 + wid * 16 + fr) * TT + P0 + fq * 8);
      c0a = cp0[0]; c0b = cp0[1];
      c1a = cp1[0]; c1b = cp1[1];
    }

    // ---- step 2: wave 0 computes Dinv from cur
    if (wid == 0) {
      const int rl = lane & 31, h2 = lane >> 5;
      float d[16];
      #pragma unroll
      for (int j = 0; j < 16; ++j) {
        const int col = P0 + h2 * 16 + j;
        d[j] = fromb(curh[col * 40 + rl]) + fromb(curl[col * 40 + rl]);
      }
      if (p == 0) gj32<true>(d, rl, h2); else gj32<false>(d, rl, h2);
      #pragma unroll
      for (int j = 0; j < 16; ++j) {
        u16 hh = bfb(d[j]);
        Dh[rl * 40 + h2 * 16 + j] = hh;
        Dl[rl * 40 + h2 * 16 + j] = bfb(d[j] - fromb(hh));
      }
    }
    __syncthreads();

    // ---- step 3: Rp = Dinv @ R, in-place into cur; write M pivot rows.
    #pragma unroll
    for (int cf = 0; cf < 2; ++cf) {
      const int j = wid * 32 + cf * 16 + fr;
      const bf16x8 bh = *(const bf16x8*)&curh[j * 40 + fq * 8];
      const bf16x8 bl = *(const bf16x8*)&curl[j * 40 + fq * 8];
      const bool inP = ((unsigned)(j - P0)) < 32u;
      const int s = j - P0;
      f32x4 acc2[2];
      #pragma unroll
      for (int fi = 0; fi < 2; ++fi) {
        const bf16x8 ah = *(const bf16x8*)&Dh[(fi * 16 + fr) * 40 + fq * 8];
        const bf16x8 al = *(const bf16x8*)&Dl[(fi * 16 + fr) * 40 + fq * 8];
        f32x4 a = {};
        a = __builtin_amdgcn_mfma_f32_16x16x32_bf16(ah, bh, a, 0, 0, 0);
        a = __builtin_amdgcn_mfma_f32_16x16x32_bf16(ah, bl, a, 0, 0, 0);
        a = __builtin_amdgcn_mfma_f32_16x16x32_bf16(al, bh, a, 0, 0, 0);
        acc2[fi] = a;
      }
      #pragma unroll
      for (int fi = 0; fi < 2; ++fi) {
        ushort4 oh, ol;
        u16* hp = (u16*)&oh; u16* lp = (u16*)&ol;
        float mvals[4];
        #pragma unroll
        for (int reg = 0; reg < 4; ++reg) {
          const int t = fi * 16 + fq * 4 + reg;
          float v = acc2[fi][reg];
          if (inP) v = fromb(Dh[t * 40 + s]) + fromb(Dl[t * 40 + s]);  // exact Dinv
          mvals[reg] = v;
          float rv = inP ? (v + ((t == s) ? 1.0f : 0.0f)) : v;  // staging: Dinv+I
          u16 hh = bfb(rv);
          hp[reg] = hh;
          lp[reg] = bfb(rv - fromb(hh));
        }
        *(ushort4*)&curh[j * 40 + fi * 16 + fq * 4] = oh;
        *(ushort4*)&curl[j * 40 + fi * 16 + fq * 4] = ol;
        #pragma unroll
        for (int reg = 0; reg < 4; ++reg)
          M[(long long)(P0 + fi * 16 + fq * 4 + reg) * TT + j] = mvals[reg];
      }
    }
    __syncthreads();   // cur holds RpB^T for ALL columns

    // ---- step 4: rank-32 update, 2 unrolled chunks of 128 rows.
    #pragma unroll
    for (int ch = 0; ch < 2; ++ch) {
      const int r0 = ch * 128 + wid * 16;
      const float4 ca = ch ? c1a : c0a;
      const float4 cb2 = ch ? c1b : c0b;
      bf16x8 ah, al;
      {
        float cv[8] = {ca.x, ca.y, ca.z, ca.w, cb2.x, cb2.y, cb2.z, cb2.w};
        u16 hbuf[8], lbuf[8];
        #pragma unroll
        for (int e = 0; e < 8; ++e) {
          float x = -cv[e];
          u16 h = bfb(x);
          hbuf[e] = h; lbuf[e] = bfb(x - fromb(h));
        }
        ah = *(const bf16x8*)hbuf;
        al = *(const bf16x8*)lbuf;
      }
      f32x4 acc[16];
      #pragma unroll
      for (int cf = 0; cf < 16; ++cf) {
        const int j = cf * 16 + fr;
        const bf16x8 bh = *(const bf16x8*)&curh[j * 40 + fq * 8];
        const bf16x8 bl = *(const bf16x8*)&curl[j * 40 + fq * 8];
        f32x4 a = {};
        a = __builtin_amdgcn_mfma_f32_16x16x32_bf16(ah, bh, a, 0, 0, 0);
        a = __builtin_amdgcn_mfma_f32_16x16x32_bf16(ah, bl, a, 0, 0, 0);
        a = __builtin_amdgcn_mfma_f32_16x16x32_bf16(al, bh, a, 0, 0, 0);
        acc[cf] = a;
      }
      #pragma unroll
      for (int reg = 0; reg < 4; ++reg) {
        const int m = r0 + fq * 4 + reg;
        if ((unsigned)(m - P0) < 32u) continue;   // pivot rows done in step 3
        float* Mrow = M + (long long)m * TT + fr;
        float mv[16];
        #pragma unroll
        for (int cf = 0; cf < 16; ++cf) mv[cf] = Mrow[cf * 16];
        #pragma unroll
        for (int cf = 0; cf < 16; ++cf) mv[cf] += acc[cf][reg];
        #pragma unroll
        for (int cf = 0; cf < 16; ++cf) Mrow[cf * 16] = mv[cf];
        // export next panel's R rows (replaces staging; same fp32 values)
        if (pi < 7 && (unsigned)(m - P0n) < 32u) {
          const int t = m - P0n;
          #pragma unroll
          for (int cf = 0; cf < 16; ++cf) {
            const int j = cf * 16 + fr;
            u16 hh = bfb(mv[cf]);
            nxth[j * 40 + t] = hh;
            nxtl[j * 40 + t] = bfb(mv[cf] - fromb(hh));
          }
        }
      }
    }
    __syncthreads();   // M + nxt ready before next panel

    // ping-pong RT buffers
    u16* th_ = curh; curh = nxth; nxth = th_;
    u16* tl_ = curl; curl = nxtl; nxtl = tl_;
  }
}

// Tiled output epilogue (verified round 10): 64x64 tiles, LDS transpose,
// coalesced A and Linv^T access.
__global__ __launch_bounds__(256) void out_tile_kernel(
    const float* __restrict__ Aall, const float* __restrict__ Linv,
    const float* __restrict__ f, float* __restrict__ out) {
  __shared__ float As[64][65];
  __shared__ float Ls[64][65];
  __shared__ float dg[64], l0v[64], fv[64];
  const int b = blockIdx.x, i0 = blockIdx.y * 64, j0 = blockIdx.z * 64;
  const float* Ab = Aall + (long long)b * TT * TT;
  const float* Lb = Linv + (long long)b * TT * TT;
  const int tid = threadIdx.x;
  #pragma unroll
  for (int q = 0; q < 16; ++q) {
    int idx = q * 256 + tid;
    int ii = idx >> 6, jj = idx & 63;
    As[ii][jj] = Ab[(long long)(i0 + ii) * TT + j0 + jj];      // A[i][j], j fast
    Ls[ii][jj] = Lb[(long long)(j0 + ii) * TT + i0 + jj];      // Linv[j][i], i fast
  }
  if (tid < 64) {
    dg[tid]  = Lb[(long long)(j0 + tid) * TT + j0 + tid];
    l0v[tid] = Lb[(long long)(j0 + tid) * TT];
    fv[tid]  = f[b * TT + j0 + tid];
  }
  __syncthreads();
  #pragma unroll
  for (int q = 0; q < 16; ++q) {
    int idx = q * 256 + tid;
    int jj = idx >> 6, ii = idx & 63;                           // ii fast -> coalesced write
    int i = i0 + ii, j = j0 + jj;
    float t1 = (j > 0) ? dg[jj] : 0.f;
    float t2 = (i > 0) ? Ls[jj][ii] : 0.f;
    out[(long long)(b * TT + j) * (TT + 1) + i + 1] = As[ii][jj] * (t1 - t2);
  }
  if (i0 == 0 && tid < 64) {
    int j = j0 + tid;
    out[(long long)(b * TT + j) * (TT + 1)] = fv[tid] * l0v[tid];
  }
}

extern "C" void kernel_launch(void* const* d_in, const int* in_sizes, int n_in,
                              void* d_out, int out_size, void* d_ws, size_t ws_size,
                              hipStream_t stream) {
  const float* inp = (const float*)d_in[0];
  const float* Wk  = (const float*)d_in[1];
  const float* bk  = (const float*)d_in[2];
  const float* Wq  = (const float*)d_in[3];
  const float* bq  = (const float*)d_in[4];
  const float* Wr  = (const float*)d_in[5];
  const float* br  = (const float*)d_in[6];
  float* out = (float*)d_out;

  // workspace layout (~114 MiB peak; 126 MiB proven available round 1)
  const long long NI = (long long)BB * TT * DD;   // 12,582,912
  u16* inpHi = (u16*)d_ws;
  u16* inpLo = inpHi + NI;
  u16* Zhi   = inpLo + NI;
  u16* Zlo   = Zhi + NI;
  u16* HTh   = Zlo + NI;
  u16* HTl   = HTh + (long long)DD * DD;
  u16* WqTh  = HTl + (long long)DD * DD;          // region later reused by A_
  u16* WqTl  = WqTh + (long long)DD * DD;
  u16* WkTh  = WqTl + (long long)DD * DD;
  u16* WkTl  = WkTh + (long long)DD * DD;
  float* A_  = (float*)WqTh;                      // aliases WqT/WkT (dead by einsum)
  float* f   = A_ + (long long)BB * TT * TT;
  float* cs  = f + BB * TT;
  float* us  = cs + BB * TT;
  float* vs_ = us + DD;
  float* spu = vs_ + DD;
  float* spv = spu + BB * TT;
  float* c0f = spv + BB * TT;
  // Z region reused: HT split-K partials (before Z), then L (after einsum)
  float* HTpart = (float*)Zhi;                    // 4 x DD x DD f32 = 16 MB
  float* L   = (float*)Zhi;

  (void)hipFuncSetAttribute(reinterpret_cast<const void*>(&pg_kernel<0>),
                            hipFuncAttributeMaxDynamicSharedMemorySize, 65536);
  (void)hipFuncSetAttribute(reinterpret_cast<const void*>(&pg_kernel<1>),
                            hipFuncAttributeMaxDynamicSharedMemorySize, 65536);
  (void)hipFuncSetAttribute(reinterpret_cast<const void*>(&pg_kernel<2>),
                            hipFuncAttributeMaxDynamicSharedMemorySize, 65536);
  (void)hipFuncSetAttribute(reinterpret_cast<const void*>(&gj_single),
                            hipFuncAttributeMaxDynamicSharedMemorySize, G3_LDS);

  const float s = 0.03125f;
  const int M = BB * TT;  // 12288

  // 1. fused prep: split(inp) + transpose+split(Wq,Wk) + c0
  prep_kernel<<<NSPLIT + 2048 + 1, 256, 0, stream>>>(
      inp, Wq, Wk, bq, bk, inpHi, inpLo, WqTh, WqTl, WkTh, WkTl, c0f);

  // 2. us = s*WqT.bk ; vs = s*WkT.bq  (one fused launch)
  rootv_pair<<<dim3(DD / 4, 2), 256, 0, stream>>>(WqTh, WqTl, WkTh, WkTl, bk, bq, us, vs_);

  // 3. HT[e,d] = sum_n Wk[n,e]*Wq[n,d] via split-K (4 partials) + combine
  pg_kernel<2><<<dim3(8, 8, 4), 256, 65536, stream>>>(
      WkTh, WkTl, WqTh, WqTl, nullptr, nullptr, HTpart, nullptr, nullptr, nullptr,
      0.f, 256, DD, DD, 256, 256, (long long)DD * DD);
  combine_ht<<<DD * DD / 4 / 256, 256, 0, stream>>>(HTpart, HTh, HTl);

  // 4. Z = X @ H  (overwrites HTpart region — stream-ordered after combine)
  pg_kernel<0><<<dim3(M / 128, DD / 128, 1), 256, 65536, stream>>>(
      inpHi, inpLo, HTh, HTl, Zhi, Zlo, nullptr, nullptr, nullptr, nullptr,
      0.f, DD, DD, DD, 0, 0, 0);

  // 5. fused row dots: f = X.Wr+br ; spu = X.us+c0 ; spv = X.vs ; cs = 0
  rootv3_kernel<<<M / 4, 256, 0, stream>>>(inp, Wr, br, us, vs_, c0f, f, spu, spv, cs);

  // 6. A[b,t,s] = (t==s)?0:exp(s*(z_t.x_s)+spu+spv), + colsum atomics into cs
  pg_kernel<1><<<dim3(TT / 128, TT / 128, BB), 256, 65536, stream>>>(
      Zhi, Zlo, inpHi, inpLo, nullptr, nullptr, A_, spu, spv, cs,
      s, DD, TT, DD, (long long)TT * DD, (long long)TT * DD, (long long)TT * TT);

  // 7. Laplacian build (colsum already in cs)
  csbl_kernel<<<dim3(BB, 4), 256, 0, stream>>>(A_, f, cs, L);

  // 8. single-block-per-matrix blocked Gauss-Jordan (panels 1..7 then 0)
  gj_single<<<BB, 512, G3_LDS, stream>>>(L);

  // 9. tiled output epilogue (coalesced A and Linv^T access)
  out_tile_kernel<<<dim3(BB, 4, 4), 256, 0, stream>>>(A_, L, f, out);
}